// Round 1
// baseline (970.461 us; speedup 1.0000x reference)
//
#include <hip/hip_runtime.h>
#include <math.h>

#define NTOK 2304      // 48*48 tokens
#define BATCH 2
#define CIN 256
#define HID 512        // 8 heads * 64
#define QKV_ROWS 1536  // 3 * HID
#define HD 64
#define NH 8

// ---------------------------------------------------------------------------
// Generic fp32 GEMM: Y[b][o][n] = sum_c A[o][c] * X[b][c][n] (+ bias[o])
// A: M x K row-major. X: B x K x NTOK. 64x64 output tile, 16-wide k tile.
// block = 256 threads (16x16), each thread computes 4x4 outputs.
// ---------------------------------------------------------------------------
__global__ __launch_bounds__(256) void gemm_kernel(
    const float* __restrict__ A,
    const float* __restrict__ X,
    const float* __restrict__ bias,
    float* __restrict__ Y,
    int M, int K)
{
    const int N = NTOK;
    int b  = blockIdx.z;
    int o0 = blockIdx.y * 64;
    int n0 = blockIdx.x * 64;

    __shared__ float As[64][17];  // [oo][kk], pad 17 -> conflict-free
    __shared__ float Bs[16][65];  // [kk][nn], pad 65 -> 2-way max (free)

    int tid = threadIdx.x;
    int tx = tid & 15, ty = tid >> 4;

    const float* Xb = X + (size_t)b * K * N;

    float acc[4][4];
#pragma unroll
    for (int i = 0; i < 4; i++)
#pragma unroll
        for (int j = 0; j < 4; j++) acc[i][j] = 0.f;

    for (int kt = 0; kt < K; kt += 16) {
        // stage A tile: 64 rows x 16 k, float4 per thread
        {
            int oo = tid >> 2, kk0 = (tid & 3) << 2;
            float4 v = *(const float4*)(A + (size_t)(o0 + oo) * K + kt + kk0);
            As[oo][kk0 + 0] = v.x; As[oo][kk0 + 1] = v.y;
            As[oo][kk0 + 2] = v.z; As[oo][kk0 + 3] = v.w;
        }
        // stage X tile: 16 k x 64 n, coalesced across n
        {
            int nn = tid & 63, kk = tid >> 6;
#pragma unroll
            for (int r = 0; r < 4; r++)
                Bs[kk + 4 * r][nn] = Xb[(size_t)(kt + kk + 4 * r) * N + n0 + nn];
        }
        __syncthreads();
#pragma unroll
        for (int kk = 0; kk < 16; kk++) {
            float a[4], bv[4];
#pragma unroll
            for (int i = 0; i < 4; i++) a[i] = As[ty * 4 + i][kk];
#pragma unroll
            for (int j = 0; j < 4; j++) bv[j] = Bs[kk][tx * 4 + j];
#pragma unroll
            for (int i = 0; i < 4; i++)
#pragma unroll
                for (int j = 0; j < 4; j++) acc[i][j] += a[i] * bv[j];
        }
        __syncthreads();
    }

#pragma unroll
    for (int i = 0; i < 4; i++) {
        int o = o0 + ty * 4 + i;
        float bb = bias ? bias[o] : 0.f;
        float* dst = Y + ((size_t)b * M + o) * N + n0 + tx * 4;
#pragma unroll
        for (int j = 0; j < 4; j++) dst[j] = acc[i][j] + bb;
    }
}

// ---------------------------------------------------------------------------
// L2-normalize each (b, o) row over the token dim for o in [0, 1024)
// (q and k parts of qkv). One block per row.
// ---------------------------------------------------------------------------
__global__ __launch_bounds__(256) void l2norm_kernel(float* __restrict__ qkv)
{
    int row = blockIdx.x;           // 0..2047
    int b = row >> 10, o = row & 1023;
    float* p = qkv + ((size_t)b * QKV_ROWS + o) * NTOK;
    int tid = threadIdx.x;

    float s = 0.f;
    for (int n = tid; n < NTOK; n += 256) { float v = p[n]; s += v * v; }
#pragma unroll
    for (int off = 32; off > 0; off >>= 1) s += __shfl_down(s, off, 64);

    __shared__ float ws[4];
    if ((tid & 63) == 0) ws[tid >> 6] = s;
    __syncthreads();
    float tot = ws[0] + ws[1] + ws[2] + ws[3];
    float inv = 1.f / fmaxf(sqrtf(tot), 1e-12f);
    for (int n = tid; n < NTOK; n += 256) p[n] *= inv;
}

// ---------------------------------------------------------------------------
// Fused flash-style attention per (b, h): O[d,n] = sum_m softmax_m(Q^T K) V[d,m]
// Q,K,V are 64 x 2304 (d-major). Block handles 64 n-columns, loops over
// 64-wide m tiles with online softmax. block = 256 threads.
// Thread map: tx = tid&63, ty = tid>>6.
//   S phase: thread computes S[ty*16+j][tx] (m = tx)
//   O phase: thread owns acc[j] for (d = ty*16+j, n = tx)
// ---------------------------------------------------------------------------
__global__ __launch_bounds__(256) void attn_kernel(
    const float* __restrict__ qkv,   // B x 1536 x NTOK
    float* __restrict__ out)         // B x 512  x NTOK
{
    const int N = NTOK;
    int bh = blockIdx.y;
    int b = bh >> 3, h = bh & 7;
    int n0 = blockIdx.x * 64;

    const float* Q  = qkv + ((size_t)b * QKV_ROWS +        h * HD) * N;
    const float* Kp = qkv + ((size_t)b * QKV_ROWS +  512 + h * HD) * N;
    const float* Vp = qkv + ((size_t)b * QKV_ROWS + 1024 + h * HD) * N;

    __shared__ float sQ[64][68];    // [d][n] pad 68: float4-aligned, broadcast reads
    __shared__ float sKV[64][68];   // [d][m] K then V (reused)
    __shared__ float sS[64][65];    // [n][m] scores/probs, pad 65: 2-way max
    __shared__ float rmax[64], rsum[64], ralpha[64];

    int tid = threadIdx.x;
    int tx = tid & 63, ty = tid >> 6;

    for (int d = ty; d < 64; d += 4)
        sQ[d][tx] = Q[(size_t)d * N + n0 + tx];
    if (ty == 0) { rmax[tx] = -1e30f; rsum[tx] = 0.f; }

    float acc[16];
#pragma unroll
    for (int j = 0; j < 16; j++) acc[j] = 0.f;

    for (int m0 = 0; m0 < N; m0 += 64) {
        __syncthreads();   // protect sKV/sS from previous iteration's readers
        for (int d = ty; d < 64; d += 4)
            sKV[d][tx] = Kp[(size_t)d * N + m0 + tx];
        __syncthreads();

        // ---- S = Q^T K tile; thread: m = tx, n = ty*16 + j
        {
            float s[16];
#pragma unroll
            for (int j = 0; j < 16; j++) s[j] = 0.f;
            int nb = ty * 16;
            for (int d = 0; d < 64; d++) {
                float kv = sKV[d][tx];                              // stride-1
                float4 q0 = *(const float4*)&sQ[d][nb + 0];          // broadcast b128
                float4 q1 = *(const float4*)&sQ[d][nb + 4];
                float4 q2 = *(const float4*)&sQ[d][nb + 8];
                float4 q3 = *(const float4*)&sQ[d][nb + 12];
                s[0] += q0.x * kv; s[1] += q0.y * kv; s[2]  += q0.z * kv; s[3]  += q0.w * kv;
                s[4] += q1.x * kv; s[5] += q1.y * kv; s[6]  += q1.z * kv; s[7]  += q1.w * kv;
                s[8] += q2.x * kv; s[9] += q2.y * kv; s[10] += q2.z * kv; s[11] += q2.w * kv;
                s[12]+= q3.x * kv; s[13]+= q3.y * kv; s[14] += q3.z * kv; s[15] += q3.w * kv;
            }
#pragma unroll
            for (int j = 0; j < 16; j++) sS[nb + j][tx] = s[j];
        }
        __syncthreads();

        // ---- online softmax row stats; one lane per row n = tx
        if (ty == 0) {
            float mprev = rmax[tx];
            float mx = mprev;
#pragma unroll 8
            for (int m = 0; m < 64; m++) mx = fmaxf(mx, sS[tx][m]);
            float alpha = __expf(mprev - mx);
            float ps = 0.f;
#pragma unroll 8
            for (int m = 0; m < 64; m++) {
                float p = __expf(sS[tx][m] - mx);
                sS[tx][m] = p;
                ps += p;
            }
            rsum[tx] = rsum[tx] * alpha + ps;
            rmax[tx] = mx;
            ralpha[tx] = alpha;
        }
        __syncthreads();

        // ---- stage V into sKV (K no longer needed)
        for (int d = ty; d < 64; d += 4)
            sKV[d][tx] = Vp[(size_t)d * N + m0 + tx];
        __syncthreads();

        // ---- O += P V^T; thread: n = tx, d = ty*16 + j
        {
            float alpha = ralpha[tx];
#pragma unroll
            for (int j = 0; j < 16; j++) acc[j] *= alpha;
            int db = ty * 16;
            for (int m = 0; m < 64; m += 4) {
                float p0 = sS[tx][m + 0];   // 2-way max (pad 65) -> free
                float p1 = sS[tx][m + 1];
                float p2 = sS[tx][m + 2];
                float p3 = sS[tx][m + 3];
#pragma unroll
                for (int j = 0; j < 16; j++) {
                    float4 kv = *(const float4*)&sKV[db + j][m];  // broadcast b128
                    acc[j] += p0 * kv.x + p1 * kv.y + p2 * kv.z + p3 * kv.w;
                }
            }
        }
    }

    float inv = 1.f / rsum[tx];
#pragma unroll
    for (int j = 0; j < 16; j++) {
        int d = ty * 16 + j;
        out[((size_t)b * HID + h * HD + d) * N + n0 + tx] = acc[j] * inv;
    }
}

// ---------------------------------------------------------------------------
extern "C" void kernel_launch(void* const* d_in, const int* in_sizes, int n_in,
                              void* d_out, int out_size, void* d_ws, size_t ws_size,
                              hipStream_t stream)
{
    const float* x      = (const float*)d_in[0];   // (2, 256, 48, 48)
    const float* w_qkv  = (const float*)d_in[1];   // (1536, 256)
    const float* w_proj = (const float*)d_in[2];   // (256, 512)
    const float* b_proj = (const float*)d_in[3];   // (256,)
    float* y = (float*)d_out;                       // (2, 256, 48, 48)

    float* qkv      = (float*)d_ws;                              // 2*1536*2304 = 28.3 MB
    float* attn_out = qkv + (size_t)BATCH * QKV_ROWS * NTOK;     // 2*512*2304  =  9.4 MB

    // 1) qkv = w_qkv @ x          (M=1536, K=256)
    gemm_kernel<<<dim3(NTOK / 64, QKV_ROWS / 64, BATCH), 256, 0, stream>>>(
        w_qkv, x, nullptr, qkv, QKV_ROWS, CIN);

    // 2) L2-normalize q and k rows over tokens (rows 0..1023 per batch)
    l2norm_kernel<<<2048, 256, 0, stream>>>(qkv);

    // 3) fused attention per (b, h), 36 n-tiles each
    attn_kernel<<<dim3(NTOK / 64, BATCH * NH), 256, 0, stream>>>(qkv, attn_out);

    // 4) y = w_proj @ attn_out + b_proj   (M=256, K=512)
    gemm_kernel<<<dim3(NTOK / 64, CIN / 64, BATCH), 256, 0, stream>>>(
        w_proj, attn_out, b_proj, y, CIN, HID);
}

// Round 2
// 304.773 us; speedup vs baseline: 3.1842x; 3.1842x over previous
//
#include <hip/hip_runtime.h>
#include <math.h>

#define NTOK 2304      // 48*48 tokens
#define BATCH 2
#define CIN 256
#define HID 512        // 8 heads * 64
#define QKV_ROWS 1536  // 3 * HID
#define NH 8

typedef __attribute__((ext_vector_type(8))) short bfrag;    // 8 bf16 (4 VGPRs)
typedef __attribute__((ext_vector_type(16))) float f32x16;  // MFMA 32x32 accumulator

// fp32 -> bf16 (RNE)
__device__ __forceinline__ unsigned f2bf(float f) {
    unsigned u = __float_as_uint(f);
    u += 0x7FFF + ((u >> 16) & 1);
    return u >> 16;
}

// ---------------------------------------------------------------------------
// Generic fp32 GEMM: Y[b][o][n] = sum_c A[o][c] * X[b][c][n] (+ bias[o])
// ---------------------------------------------------------------------------
__global__ __launch_bounds__(256) void gemm_kernel(
    const float* __restrict__ A,
    const float* __restrict__ X,
    const float* __restrict__ bias,
    float* __restrict__ Y,
    int M, int K)
{
    const int N = NTOK;
    int b  = blockIdx.z;
    int o0 = blockIdx.y * 64;
    int n0 = blockIdx.x * 64;

    __shared__ float As[64][17];
    __shared__ float Bs[16][65];

    int tid = threadIdx.x;
    int tx = tid & 15, ty = tid >> 4;

    const float* Xb = X + (size_t)b * K * N;

    float acc[4][4];
#pragma unroll
    for (int i = 0; i < 4; i++)
#pragma unroll
        for (int j = 0; j < 4; j++) acc[i][j] = 0.f;

    for (int kt = 0; kt < K; kt += 16) {
        {
            int oo = tid >> 2, kk0 = (tid & 3) << 2;
            float4 v = *(const float4*)(A + (size_t)(o0 + oo) * K + kt + kk0);
            As[oo][kk0 + 0] = v.x; As[oo][kk0 + 1] = v.y;
            As[oo][kk0 + 2] = v.z; As[oo][kk0 + 3] = v.w;
        }
        {
            int nn = tid & 63, kk = tid >> 6;
#pragma unroll
            for (int r = 0; r < 4; r++)
                Bs[kk + 4 * r][nn] = Xb[(size_t)(kt + kk + 4 * r) * N + n0 + nn];
        }
        __syncthreads();
#pragma unroll
        for (int kk = 0; kk < 16; kk++) {
            float a[4], bv[4];
#pragma unroll
            for (int i = 0; i < 4; i++) a[i] = As[ty * 4 + i][kk];
#pragma unroll
            for (int j = 0; j < 4; j++) bv[j] = Bs[kk][tx * 4 + j];
#pragma unroll
            for (int i = 0; i < 4; i++)
#pragma unroll
                for (int j = 0; j < 4; j++) acc[i][j] += a[i] * bv[j];
        }
        __syncthreads();
    }

#pragma unroll
    for (int i = 0; i < 4; i++) {
        int o = o0 + ty * 4 + i;
        float bb = bias ? bias[o] : 0.f;
        float* dst = Y + ((size_t)b * M + o) * N + n0 + tx * 4;
#pragma unroll
        for (int j = 0; j < 4; j++) dst[j] = acc[i][j] + bb;
    }
}

// ---------------------------------------------------------------------------
// In-place L2-normalize each (b, o) row over tokens, o in [0, 1024) (q and k)
// ---------------------------------------------------------------------------
__global__ __launch_bounds__(256) void l2norm_kernel(float* __restrict__ qkv)
{
    int row = blockIdx.x;           // 0..2047
    int b = row >> 10, o = row & 1023;
    float* p = qkv + ((size_t)b * QKV_ROWS + o) * NTOK;
    int tid = threadIdx.x;

    float s = 0.f;
    for (int n = tid; n < NTOK; n += 256) { float v = p[n]; s += v * v; }
#pragma unroll
    for (int off = 32; off > 0; off >>= 1) s += __shfl_down(s, off, 64);

    __shared__ float ws[4];
    if ((tid & 63) == 0) ws[tid >> 6] = s;
    __syncthreads();
    float tot = ws[0] + ws[1] + ws[2] + ws[3];
    float inv = 1.f / fmaxf(sqrtf(tot), 1e-12f);
    for (int n = tid; n < NTOK; n += 256) p[n] *= inv;
}

// ---------------------------------------------------------------------------
// Pack normalized q,k (fp32 [d][n]) -> bf16 token-major [n][d] via LDS transpose.
// qkt layout: [sel][bh][n][64d] bf16. grid (36 n-tiles, 16 bh, 2 sel)
// ---------------------------------------------------------------------------
__global__ __launch_bounds__(256) void pack_qk(
    const float* __restrict__ qkv, short* __restrict__ qkt)
{
    int n0 = blockIdx.x * 64;
    int bh = blockIdx.y;
    int sel = blockIdx.z;
    int b = bh >> 3, h = bh & 7;
    const float* src = qkv + ((size_t)b * QKV_ROWS + sel * 512 + h * 64) * NTOK;

    __shared__ float sT[64][65];
    int tid = threadIdx.x;
    int lane = tid & 63, wv = tid >> 6;
    for (int d = wv; d < 64; d += 4)
        sT[d][lane] = src[(size_t)d * NTOK + n0 + lane];
    __syncthreads();

    int n = tid >> 2, c4 = (tid & 3) * 16;
    unsigned buf[8];
#pragma unroll
    for (int i = 0; i < 8; i++) {
        unsigned lo = f2bf(sT[c4 + 2 * i][n]);
        unsigned hi = f2bf(sT[c4 + 2 * i + 1][n]);
        buf[i] = lo | (hi << 16);
    }
    short* dst = qkt + (size_t)sel * ((size_t)16 * NTOK * 64)
                     + ((size_t)bh * NTOK + n0 + n) * 64 + c4;
    ((uint4*)dst)[0] = make_uint4(buf[0], buf[1], buf[2], buf[3]);
    ((uint4*)dst)[1] = make_uint4(buf[4], buf[5], buf[6], buf[7]);
}

// ---------------------------------------------------------------------------
// Pack v fp32 [d][m] -> bf16 [d][m] elementwise. 8 elems / thread.
// ---------------------------------------------------------------------------
__global__ __launch_bounds__(256) void pack_v(
    const float* __restrict__ qkv, short* __restrict__ vb)
{
    size_t gid = (size_t)blockIdx.x * 256 + threadIdx.x;
    size_t e = gid * 8;                            // < 2*512*2304
    int b = (int)(e / ((size_t)512 * NTOK));
    size_t rem = e - (size_t)b * 512 * NTOK;
    const float* src = qkv + ((size_t)b * QKV_ROWS + 1024) * NTOK + rem;
    float4 v0 = ((const float4*)src)[0];
    float4 v1 = ((const float4*)src)[1];
    unsigned b0 = f2bf(v0.x) | (f2bf(v0.y) << 16);
    unsigned b1 = f2bf(v0.z) | (f2bf(v0.w) << 16);
    unsigned b2 = f2bf(v1.x) | (f2bf(v1.y) << 16);
    unsigned b3 = f2bf(v1.z) | (f2bf(v1.w) << 16);
    *((uint4*)(vb + (size_t)b * 512 * NTOK + rem)) = make_uint4(b0, b1, b2, b3);
}

// ---------------------------------------------------------------------------
// MFMA flash attention. Block = 4 waves, 64 n-cols, loop over 64-wide m tiles.
// Wave w: S quadrant (qn=w&1, qm=w>>1); O quadrant (qd=w>>1, qn=w&1).
// A(Q^T) frags live in registers across the whole m-loop.
// ---------------------------------------------------------------------------
__global__ __launch_bounds__(256) void attn_mfma(
    const short* __restrict__ qkt,   // [2][16][2304][64] bf16
    const short* __restrict__ vb,    // [16][64][2304] bf16
    float* __restrict__ out)         // [2][512][2304] fp32
{
    int bh = blockIdx.y;
    int n0 = blockIdx.x * 64;

    const short* Qt = qkt + (size_t)bh * NTOK * 64;
    const short* Kt = qkt + (size_t)16 * NTOK * 64 + (size_t)bh * NTOK * 64;
    const short* Vb = vb + (size_t)bh * 64 * NTOK;

    __shared__ float sS[64][65];     // scores [n][m], pitch 65 -> 2-way max
    __shared__ short sPb[64][66];    // probs bf16 [n][m], pitch 66 (dword 33) -> 2-way
    __shared__ float sRedM[4][64];
    __shared__ float sRedS[4][64];
    __shared__ float stM[64], stS[64], stA[64];

    int tid = threadIdx.x;
    int wv = tid >> 6, lane = tid & 63;
    int half = lane >> 5, l31 = lane & 31;
    int qn = wv & 1, qhi = wv >> 1;

    // A-frags of S: Q^T rows n = n0 + qn*32 + l31, k=d chunks of 16
    bfrag aQ[4];
    {
        const short* qrow = Qt + (size_t)(n0 + qn * 32 + l31) * 64 + half * 8;
#pragma unroll
        for (int i = 0; i < 4; i++)
            aQ[i] = *(const bfrag*)(qrow + i * 16);
    }
    if (tid < 64) { stM[tid] = -1e30f; stS[tid] = 0.f; }

    f32x16 accO;
#pragma unroll
    for (int r = 0; r < 16; r++) accO[r] = 0.f;

    for (int m0 = 0; m0 < NTOK; m0 += 64) {
        // ---- S = Q^T K quadrant: 4 MFMA over d
        f32x16 accS;
#pragma unroll
        for (int r = 0; r < 16; r++) accS[r] = 0.f;
        const short* krow = Kt + (size_t)(m0 + qhi * 32 + l31) * 64 + half * 8;
#pragma unroll
        for (int i = 0; i < 4; i++) {
            bfrag bK = *(const bfrag*)(krow + i * 16);
            accS = __builtin_amdgcn_mfma_f32_32x32x16_bf16(aQ[i], bK, accS, 0, 0, 0);
        }
        // C layout: col=lane&31 (m), row=(r&3)+8*(r>>2)+4*half (n)
#pragma unroll
        for (int r = 0; r < 16; r++) {
            int rr = qn * 32 + (r & 3) + 8 * (r >> 2) + 4 * half;
            sS[rr][qhi * 32 + l31] = accS[r];
        }
        __syncthreads();                                    // B2

        // ---- pass 1: partial row max (thread: row=lane, m-chunk=wv)
        float pmax = -1e30f;
#pragma unroll
        for (int i = 0; i < 16; i++) pmax = fmaxf(pmax, sS[lane][wv * 16 + i]);
        sRedM[wv][lane] = pmax;
        __syncthreads();                                    // B3

        float mprev = stM[lane];
        float mx = fmaxf(mprev, fmaxf(fmaxf(sRedM[0][lane], sRedM[1][lane]),
                                      fmaxf(sRedM[2][lane], sRedM[3][lane])));
        float alpha = __expf(mprev - mx);

        // ---- pass 2: exp, write p as bf16 (sum from the rounded values)
        float psum = 0.f;
#pragma unroll
        for (int i = 0; i < 8; i++) {
            float p0 = __expf(sS[lane][wv * 16 + 2 * i] - mx);
            float p1 = __expf(sS[lane][wv * 16 + 2 * i + 1] - mx);
            unsigned lo = f2bf(p0), hi = f2bf(p1);
            psum += __uint_as_float(lo << 16) + __uint_as_float(hi << 16);
            *(unsigned*)&sPb[lane][wv * 16 + 2 * i] = lo | (hi << 16);
        }
        sRedS[wv][lane] = psum;
        __syncthreads();                                    // B4

        if (wv == 0) {
            float s4 = sRedS[0][lane] + sRedS[1][lane] + sRedS[2][lane] + sRedS[3][lane];
            stS[lane] = stS[lane] * alpha + s4;
            stM[lane] = mx;
            stA[lane] = alpha;
        }
        __syncthreads();                                    // B5

        // ---- O quadrant (qd=qhi, qn): acc rescale + 4 MFMA (A=V, B=P^T)
        float al = stA[qn * 32 + l31];
#pragma unroll
        for (int r = 0; r < 16; r++) accO[r] *= al;
        const short* vrow = Vb + (size_t)(qhi * 32 + l31) * NTOK + m0 + half * 8;
        const short* prow = &sPb[qn * 32 + l31][half * 8];
#pragma unroll
        for (int i = 0; i < 4; i++) {
            bfrag aV = *(const bfrag*)(vrow + i * 16);
            union { bfrag f8; unsigned u[4]; } ub;
            const unsigned* ps = (const unsigned*)(prow + i * 16);
            ub.u[0] = ps[0]; ub.u[1] = ps[1]; ub.u[2] = ps[2]; ub.u[3] = ps[3];
            accO = __builtin_amdgcn_mfma_f32_32x32x16_bf16(aV, ub.f8, accO, 0, 0, 0);
        }
    }

    // epilogue: O[d][n] / l_n  (C layout: col=n, row=d)
    float inv = 1.f / stS[qn * 32 + l31];
    float* orow = out + (size_t)bh * 64 * NTOK;
#pragma unroll
    for (int r = 0; r < 16; r++) {
        int d = qhi * 32 + (r & 3) + 8 * (r >> 2) + 4 * half;
        orow[(size_t)d * NTOK + n0 + qn * 32 + l31] = accO[r] * inv;
    }
}

// ---------------------------------------------------------------------------
// Workspace layout (37,748,736 B total — identical footprint to R1):
//   [0, 28311552)          qkv fp32 [2][1536][2304]
//   [4718592, 9437184)     vb bf16   (aliases k(b=0) fp32 — dead after pack_qk)
//   [9437184, 18874368)    attn_out  (aliases v(b=0)+q(b=1) fp32 — dead after pack)
//   [28311552, 37748736)   qkt bf16 [2][16][2304][64]
// ---------------------------------------------------------------------------
extern "C" void kernel_launch(void* const* d_in, const int* in_sizes, int n_in,
                              void* d_out, int out_size, void* d_ws, size_t ws_size,
                              hipStream_t stream)
{
    const float* x      = (const float*)d_in[0];
    const float* w_qkv  = (const float*)d_in[1];
    const float* w_proj = (const float*)d_in[2];
    const float* b_proj = (const float*)d_in[3];
    float* y = (float*)d_out;

    float* qkv      = (float*)d_ws;
    short* vb       = (short*)((char*)d_ws + 4718592);
    float* attn_out = (float*)((char*)d_ws + 9437184);
    short* qkt      = (short*)((char*)d_ws + 28311552);

    // 1) qkv = w_qkv @ x
    gemm_kernel<<<dim3(NTOK / 64, QKV_ROWS / 64, BATCH), 256, 0, stream>>>(
        w_qkv, x, nullptr, qkv, QKV_ROWS, CIN);

    // 2) in-place L2-normalize q,k rows
    l2norm_kernel<<<2048, 256, 0, stream>>>(qkv);

    // 3) pack q,k -> bf16 [n][d]; v -> bf16 [d][m]
    pack_qk<<<dim3(NTOK / 64, BATCH * NH, 2), 256, 0, stream>>>(qkv, qkt);
    pack_v<<<dim3((BATCH * 512 * NTOK / 8) / 256), 256, 0, stream>>>(qkv, vb);

    // 4) MFMA flash attention
    attn_mfma<<<dim3(NTOK / 64, BATCH * NH), 256, 0, stream>>>(qkt, vb, attn_out);

    // 5) y = w_proj @ attn_out + b_proj
    gemm_kernel<<<dim3(NTOK / 64, CIN / 64, BATCH), 256, 0, stream>>>(
        w_proj, attn_out, b_proj, y, CIN, HID);
}

// Round 3
// 239.296 us; speedup vs baseline: 4.0555x; 1.2736x over previous
//
#include <hip/hip_runtime.h>
#include <math.h>

#define NTOK 2304      // 48*48 tokens
#define BATCH 2
#define CIN 256
#define HID 512        // 8 heads * 64
#define QKV_ROWS 1536  // 3 * HID
#define NH 8

typedef __attribute__((ext_vector_type(8))) short bfrag;    // 8 bf16 (4 VGPRs)
typedef __attribute__((ext_vector_type(16))) float f32x16;  // MFMA 32x32 accumulator

// fp32 -> bf16 (RNE)
__device__ __forceinline__ unsigned f2bf(float f) {
    unsigned u = __float_as_uint(f);
    u += 0x7FFF + ((u >> 16) & 1);
    return u >> 16;
}

// ---------------------------------------------------------------------------
// Elementwise fp32 -> bf16 pack (row-major preserved). 8 elems/thread.
// ---------------------------------------------------------------------------
__global__ __launch_bounds__(256) void pack_bf16(
    const float* __restrict__ src, short* __restrict__ dst, int n)
{
    int e = (blockIdx.x * 256 + threadIdx.x) * 8;
    if (e >= n) return;
    float4 v0 = ((const float4*)(src + e))[0];
    float4 v1 = ((const float4*)(src + e))[1];
    unsigned b0 = f2bf(v0.x) | (f2bf(v0.y) << 16);
    unsigned b1 = f2bf(v0.z) | (f2bf(v0.w) << 16);
    unsigned b2 = f2bf(v1.x) | (f2bf(v1.y) << 16);
    unsigned b3 = f2bf(v1.z) | (f2bf(v1.w) << 16);
    *((uint4*)(dst + e)) = make_uint4(b0, b1, b2, b3);
}

// ---------------------------------------------------------------------------
// Transpose-pack x: fp32 [b][256][2304] -> bf16 xT [b][2304][256]
// grid (36 n-tiles, 4 c-tiles, 2 b)
// ---------------------------------------------------------------------------
__global__ __launch_bounds__(256) void pack_xT(
    const float* __restrict__ x, short* __restrict__ xT)
{
    int n0 = blockIdx.x * 64, c0 = blockIdx.y * 64, b = blockIdx.z;
    __shared__ float sT[64][65];
    int tid = threadIdx.x, lane = tid & 63, wv = tid >> 6;
    for (int c = wv; c < 64; c += 4)
        sT[c][lane] = x[((size_t)b * CIN + c0 + c) * NTOK + n0 + lane];
    __syncthreads();
    int n = tid >> 2, c4 = (tid & 3) * 16;
    unsigned buf[8];
#pragma unroll
    for (int i = 0; i < 8; i++)
        buf[i] = f2bf(sT[c4 + 2 * i][n]) | (f2bf(sT[c4 + 2 * i + 1][n]) << 16);
    short* dst = xT + ((size_t)b * NTOK + n0 + n) * CIN + c0 + c4;
    ((uint4*)dst)[0] = make_uint4(buf[0], buf[1], buf[2], buf[3]);
    ((uint4*)dst)[1] = make_uint4(buf[4], buf[5], buf[6], buf[7]);
}

// ---------------------------------------------------------------------------
// bf16 MFMA GEMM, no LDS: C[b][o][n] = sum_c A[o][c]*B[b][n][c] (+bias[o])
// A: [M][K] bf16. B: [b][NTOK][K] bf16. Block = 4 waves; BM=64, BN=128;
// wave w owns 64 x 32 (n-quadrant w). grid (NTOK/128, M/64, batch).
// ---------------------------------------------------------------------------
template<int K>
__global__ __launch_bounds__(256) void gemm_bf16(
    const short* __restrict__ A, const short* __restrict__ B,
    const float* __restrict__ bias, float* __restrict__ C, int M)
{
    int b = blockIdx.z;
    int o0 = blockIdx.y * 64;
    int n0 = blockIdx.x * 128;
    int tid = threadIdx.x, wv = tid >> 6, lane = tid & 63;
    int half = lane >> 5, l31 = lane & 31;

    const short* arow = A + (size_t)(o0 + l31) * K + half * 8;
    const short* brow = B + ((size_t)b * NTOK + n0 + wv * 32 + l31) * K + half * 8;

    f32x16 acc0, acc1;
#pragma unroll
    for (int r = 0; r < 16; r++) { acc0[r] = 0.f; acc1[r] = 0.f; }

#pragma unroll 8
    for (int kt = 0; kt < K; kt += 16) {
        bfrag a0 = *(const bfrag*)(arow + kt);
        bfrag a1 = *(const bfrag*)(arow + (size_t)32 * K + kt);
        bfrag bb = *(const bfrag*)(brow + kt);
        acc0 = __builtin_amdgcn_mfma_f32_32x32x16_bf16(a0, bb, acc0, 0, 0, 0);
        acc1 = __builtin_amdgcn_mfma_f32_32x32x16_bf16(a1, bb, acc1, 0, 0, 0);
    }

    float* Cb = C + ((size_t)b * M) * NTOK;
    int nn = n0 + wv * 32 + l31;
#pragma unroll
    for (int r = 0; r < 16; r++) {
        int ml = (r & 3) + 8 * (r >> 2) + 4 * half;
        float bi0 = bias ? bias[o0 + ml] : 0.f;
        float bi1 = bias ? bias[o0 + 32 + ml] : 0.f;
        Cb[(size_t)(o0 + ml) * NTOK + nn] = acc0[r] + bi0;
        Cb[(size_t)(o0 + 32 + ml) * NTOK + nn] = acc1[r] + bi1;
    }
}

// ---------------------------------------------------------------------------
// Row L2-norm over tokens -> invn[row], rows 0..2047 (q,k rows per batch)
// ---------------------------------------------------------------------------
__global__ __launch_bounds__(256) void rownorm(
    const float* __restrict__ qkv, float* __restrict__ invn)
{
    int row = blockIdx.x;
    int b = row >> 10, o = row & 1023;
    const float* p = qkv + ((size_t)b * QKV_ROWS + o) * NTOK;
    int tid = threadIdx.x;
    float s = 0.f;
    for (int n = tid; n < NTOK; n += 256) { float v = p[n]; s += v * v; }
#pragma unroll
    for (int off = 32; off > 0; off >>= 1) s += __shfl_down(s, off, 64);
    __shared__ float ws[4];
    if ((tid & 63) == 0) ws[tid >> 6] = s;
    __syncthreads();
    if (tid == 0) {
        float tot = ws[0] + ws[1] + ws[2] + ws[3];
        invn[row] = 1.f / fmaxf(sqrtf(tot), 1e-12f);
    }
}

// ---------------------------------------------------------------------------
// Pack q,k fp32 [d][n] -> normalized bf16 token-major qkt [sel][bh][n][64]
// grid (36, 16 bh, 2 sel)
// ---------------------------------------------------------------------------
__global__ __launch_bounds__(256) void pack_qk(
    const float* __restrict__ qkv, const float* __restrict__ invn,
    short* __restrict__ qkt)
{
    int n0 = blockIdx.x * 64;
    int bh = blockIdx.y;
    int sel = blockIdx.z;
    int b = bh >> 3, h = bh & 7;
    const float* src = qkv + ((size_t)b * QKV_ROWS + sel * 512 + h * 64) * NTOK;
    int base = b * 1024 + sel * 512 + h * 64;

    __shared__ float sT[64][65];
    int tid = threadIdx.x, lane = tid & 63, wv = tid >> 6;
    for (int d = wv; d < 64; d += 4)
        sT[d][lane] = src[(size_t)d * NTOK + n0 + lane] * invn[base + d];
    __syncthreads();

    int n = tid >> 2, c4 = (tid & 3) * 16;
    unsigned buf[8];
#pragma unroll
    for (int i = 0; i < 8; i++)
        buf[i] = f2bf(sT[c4 + 2 * i][n]) | (f2bf(sT[c4 + 2 * i + 1][n]) << 16);
    short* dst = qkt + (size_t)sel * ((size_t)16 * NTOK * 64)
                     + ((size_t)bh * NTOK + n0 + n) * 64 + c4;
    ((uint4*)dst)[0] = make_uint4(buf[0], buf[1], buf[2], buf[3]);
    ((uint4*)dst)[1] = make_uint4(buf[4], buf[5], buf[6], buf[7]);
}

// ---------------------------------------------------------------------------
// Pack v fp32 [d][m] -> bf16 [d][m]. 8 elems/thread.
// ---------------------------------------------------------------------------
__global__ __launch_bounds__(256) void pack_v(
    const float* __restrict__ qkv, short* __restrict__ vb)
{
    size_t gid = (size_t)blockIdx.x * 256 + threadIdx.x;
    size_t e = gid * 8;
    int b = (int)(e / ((size_t)512 * NTOK));
    size_t rem = e - (size_t)b * 512 * NTOK;
    const float* src = qkv + ((size_t)b * QKV_ROWS + 1024) * NTOK + rem;
    float4 v0 = ((const float4*)src)[0];
    float4 v1 = ((const float4*)src)[1];
    unsigned b0 = f2bf(v0.x) | (f2bf(v0.y) << 16);
    unsigned b1 = f2bf(v0.z) | (f2bf(v0.w) << 16);
    unsigned b2 = f2bf(v1.x) | (f2bf(v1.y) << 16);
    unsigned b3 = f2bf(v1.z) | (f2bf(v1.w) << 16);
    *((uint4*)(vb + (size_t)b * 512 * NTOK + rem)) = make_uint4(b0, b1, b2, b3);
}

// ---------------------------------------------------------------------------
// MFMA flash attention, split-m (2 halves of 18 m-tiles each).
// grid (36 n-tiles, 16 bh, 2 mhalf). Writes unnormalized O + (m,l) stats.
// Softmax: 2 barriers/iter, rows owned by 4 adjacent lanes + shfl_xor.
// ---------------------------------------------------------------------------
__global__ __launch_bounds__(256) void attn_mfma(
    const short* __restrict__ qkt,   // [2][16][2304][64] bf16
    const short* __restrict__ vb,    // [16][64][2304] bf16
    float* __restrict__ Opart,       // [2][16*64][2304] fp32 unnormalized
    float* __restrict__ statsM,      // [2][16][2304]
    float* __restrict__ statsS)      // [2][16][2304]
{
    int bh = blockIdx.y;
    int n0 = blockIdx.x * 64;
    int mhalf = blockIdx.z;
    int mbase = mhalf * (NTOK / 2);

    const short* Qt = qkt + (size_t)bh * NTOK * 64;
    const short* Kt = qkt + (size_t)16 * NTOK * 64 + (size_t)bh * NTOK * 64;
    const short* Vb = vb + (size_t)bh * 64 * NTOK;

    __shared__ float sS[64][68];     // scores [n][m], pitch 68 (16B-aligned rows)
    __shared__ short sPb[64][72];    // probs bf16 [n][m], 144B rows (16B-aligned)
    __shared__ float stM[64], stS[64], stA[64];

    int tid = threadIdx.x;
    int wv = tid >> 6, lane = tid & 63;
    int half = lane >> 5, l31 = lane & 31;
    int qn = wv & 1, qhi = wv >> 1;

    // A-frags of S: Q^T rows n = n0 + qn*32 + l31 (live whole loop)
    bfrag aQ[4];
    {
        const short* qrow = Qt + (size_t)(n0 + qn * 32 + l31) * 64 + half * 8;
#pragma unroll
        for (int i = 0; i < 4; i++) aQ[i] = *(const bfrag*)(qrow + i * 16);
    }
    if (tid < 64) { stM[tid] = -1e30f; stS[tid] = 0.f; }
    __syncthreads();

    f32x16 accO;
#pragma unroll
    for (int r = 0; r < 16; r++) accO[r] = 0.f;

    for (int mt = 0; mt < NTOK / 2; mt += 64) {
        int m0 = mbase + mt;
        // ---- S = Q^T K quadrant: 4 MFMA over d
        f32x16 accS;
#pragma unroll
        for (int r = 0; r < 16; r++) accS[r] = 0.f;
        const short* krow = Kt + (size_t)(m0 + qhi * 32 + l31) * 64 + half * 8;
#pragma unroll
        for (int i = 0; i < 4; i++) {
            bfrag bK = *(const bfrag*)(krow + i * 16);
            accS = __builtin_amdgcn_mfma_f32_32x32x16_bf16(aQ[i], bK, accS, 0, 0, 0);
        }
#pragma unroll
        for (int r = 0; r < 16; r++) {
            int rr = qn * 32 + (r & 3) + 8 * (r >> 2) + 4 * half;
            sS[rr][qhi * 32 + l31] = accS[r];
        }
        __syncthreads();                                    // B1

        // ---- softmax: row n = tid>>2, m-chunk mc = tid&3 (16 m's, float4)
        {
            int n = tid >> 2, mc = tid & 3;
            float4 s0 = *(const float4*)&sS[n][mc * 16 + 0];
            float4 s1 = *(const float4*)&sS[n][mc * 16 + 4];
            float4 s2 = *(const float4*)&sS[n][mc * 16 + 8];
            float4 s3 = *(const float4*)&sS[n][mc * 16 + 12];
            float pm = fmaxf(fmaxf(fmaxf(s0.x, s0.y), fmaxf(s0.z, s0.w)),
                             fmaxf(fmaxf(s1.x, s1.y), fmaxf(s1.z, s1.w)));
            pm = fmaxf(pm, fmaxf(fmaxf(fmaxf(s2.x, s2.y), fmaxf(s2.z, s2.w)),
                                 fmaxf(fmaxf(s3.x, s3.y), fmaxf(s3.z, s3.w))));
            pm = fmaxf(pm, __shfl_xor(pm, 1, 64));
            pm = fmaxf(pm, __shfl_xor(pm, 2, 64));
            float mprev = stM[n];
            float mx = fmaxf(mprev, pm);
            float alpha = __expf(mprev - mx);
            float sv[16] = { s0.x, s0.y, s0.z, s0.w, s1.x, s1.y, s1.z, s1.w,
                             s2.x, s2.y, s2.z, s2.w, s3.x, s3.y, s3.z, s3.w };
            unsigned pk[8];
            float psum = 0.f;
#pragma unroll
            for (int i = 0; i < 8; i++) {
                unsigned lo = f2bf(__expf(sv[2 * i] - mx));
                unsigned hi = f2bf(__expf(sv[2 * i + 1] - mx));
                psum += __uint_as_float(lo << 16) + __uint_as_float(hi << 16);
                pk[i] = lo | (hi << 16);
            }
            *(uint4*)&sPb[n][mc * 16 + 0] = make_uint4(pk[0], pk[1], pk[2], pk[3]);
            *(uint4*)&sPb[n][mc * 16 + 8] = make_uint4(pk[4], pk[5], pk[6], pk[7]);
            psum += __shfl_xor(psum, 1, 64);
            psum += __shfl_xor(psum, 2, 64);
            if (mc == 0) {
                stS[n] = stS[n] * alpha + psum;
                stM[n] = mx;
                stA[n] = alpha;
            }
        }
        __syncthreads();                                    // B2

        // ---- O quadrant: rescale + 4 MFMA (A=V rows d, B=P rows n)
        float al = stA[qn * 32 + l31];
#pragma unroll
        for (int r = 0; r < 16; r++) accO[r] *= al;
        const short* vrow = Vb + (size_t)(qhi * 32 + l31) * NTOK + m0 + half * 8;
        const short* prow = &sPb[qn * 32 + l31][half * 8];
#pragma unroll
        for (int i = 0; i < 4; i++) {
            bfrag aV = *(const bfrag*)(vrow + i * 16);
            bfrag bP = *(const bfrag*)(prow + i * 16);
            accO = __builtin_amdgcn_mfma_f32_32x32x16_bf16(aV, bP, accO, 0, 0, 0);
        }
    }

    // epilogue: unnormalized O + stats for this m-half
    float* Ob = Opart + (size_t)mhalf * (2 * 512 * NTOK) + (size_t)bh * 64 * NTOK;
#pragma unroll
    for (int r = 0; r < 16; r++) {
        int d = qhi * 32 + (r & 3) + 8 * (r >> 2) + 4 * half;
        Ob[(size_t)d * NTOK + n0 + qn * 32 + l31] = accO[r];
    }
    if (tid < 64) {
        statsM[((size_t)mhalf * 16 + bh) * NTOK + n0 + tid] = stM[tid];
        statsS[((size_t)mhalf * 16 + bh) * NTOK + n0 + tid] = stS[tid];
    }
}

// ---------------------------------------------------------------------------
// Combine two m-halves, normalize, write bf16 proj operand aoT [b][n][512].
// grid (36 n-tiles, 16 bh)
// ---------------------------------------------------------------------------
__global__ __launch_bounds__(256) void attn_combine(
    const float* __restrict__ Opart,
    const float* __restrict__ statsM, const float* __restrict__ statsS,
    short* __restrict__ aoT)
{
    int n0 = blockIdx.x * 64;
    int bh = blockIdx.y;
    int b = bh >> 3, h = bh & 7;

    __shared__ float sT[64][65];
    __shared__ float wA[64], wB[64];
    int tid = threadIdx.x, lane = tid & 63, wv = tid >> 6;

    if (tid < 64) {
        float m0 = statsM[(size_t)bh * NTOK + n0 + tid];
        float m1 = statsM[((size_t)16 + bh) * NTOK + n0 + tid];
        float l0 = statsS[(size_t)bh * NTOK + n0 + tid];
        float l1 = statsS[((size_t)16 + bh) * NTOK + n0 + tid];
        float M = fmaxf(m0, m1);
        float w0 = __expf(m0 - M), w1 = __expf(m1 - M);
        float inv = 1.f / (w0 * l0 + w1 * l1);
        wA[tid] = w0 * inv;
        wB[tid] = w1 * inv;
    }
    __syncthreads();

    const float* O0 = Opart + (size_t)bh * 64 * NTOK;
    const float* O1 = Opart + (size_t)2 * 512 * NTOK + (size_t)bh * 64 * NTOK;
    for (int d = wv; d < 64; d += 4)
        sT[d][lane] = O0[(size_t)d * NTOK + n0 + lane] * wA[lane]
                    + O1[(size_t)d * NTOK + n0 + lane] * wB[lane];
    __syncthreads();

    int n = tid >> 2, c4 = (tid & 3) * 16;
    unsigned buf[8];
#pragma unroll
    for (int i = 0; i < 8; i++)
        buf[i] = f2bf(sT[c4 + 2 * i][n]) | (f2bf(sT[c4 + 2 * i + 1][n]) << 16);
    short* dst = aoT + ((size_t)b * NTOK + n0 + n) * HID + h * 64 + c4;
    ((uint4*)dst)[0] = make_uint4(buf[0], buf[1], buf[2], buf[3]);
    ((uint4*)dst)[1] = make_uint4(buf[4], buf[5], buf[6], buf[7]);
}

// ---------------------------------------------------------------------------
// Workspace layout (total 37,748,736 B, same as R2):
//  A: [0, 28,311,552)  qkv fp32                  (live k3..k6)
//     vb bf16    [0, 4,718,592)                  (written k6, over dead q(b0))
//     Opart fp32 [4,718,592, 23,592,960)         (k7, over dead k/v/q/k fp32)
//     aoT bf16   [23,592,960, 28,311,552)        (k8, over dead v(b1) fp32)
//  B: [28,311,552, 37,748,736)
//     xT bf16  [28,311,552, 30,670,848) + wqb [30,670,848, 31,457,280) (k1-k3)
//     qkt bf16 [28,311,552, 37,748,736)          (k5, over dead xT/wqb)
//     wpb bf16 [28,311,552, 28,573,696)          (k9, over dead qkt)
//  d_out scratch (fully overwritten by final proj GEMM):
//     invn fp32 [0, 2048 floats); statsM [2048, +73728); statsS next
// ---------------------------------------------------------------------------
extern "C" void kernel_launch(void* const* d_in, const int* in_sizes, int n_in,
                              void* d_out, int out_size, void* d_ws, size_t ws_size,
                              hipStream_t stream)
{
    const float* x      = (const float*)d_in[0];
    const float* w_qkv  = (const float*)d_in[1];
    const float* w_proj = (const float*)d_in[2];
    const float* b_proj = (const float*)d_in[3];
    float* y = (float*)d_out;

    float* qkv   = (float*)d_ws;
    short* vb    = (short*)d_ws;
    float* Opart = (float*)((char*)d_ws + 4718592);
    short* aoT   = (short*)((char*)d_ws + 23592960);
    short* xT    = (short*)((char*)d_ws + 28311552);
    short* wqb   = (short*)((char*)d_ws + 30670848);
    short* qkt   = (short*)((char*)d_ws + 28311552);
    short* wpb   = (short*)((char*)d_ws + 28311552);

    float* invn   = (float*)d_out;
    float* statsM = (float*)d_out + 2048;
    float* statsS = statsM + 2 * 16 * NTOK;

    // k1: pack w_qkv -> bf16
    pack_bf16<<<QKV_ROWS * CIN / 8 / 256, 256, 0, stream>>>(w_qkv, wqb, QKV_ROWS * CIN);
    // k2: transpose-pack x -> xT bf16 [b][n][c]
    pack_xT<<<dim3(NTOK / 64, CIN / 64, BATCH), 256, 0, stream>>>(x, xT);
    // k3: qkv = w_qkv @ x (MFMA)
    gemm_bf16<CIN><<<dim3(NTOK / 128, QKV_ROWS / 64, BATCH), 256, 0, stream>>>(
        wqb, xT, nullptr, qkv, QKV_ROWS);
    // k4: row inverse L2 norms for q,k
    rownorm<<<2048, 256, 0, stream>>>(qkv, invn);
    // k5: pack normalized q,k -> qkt bf16 [n][d]
    pack_qk<<<dim3(NTOK / 64, BATCH * NH, 2), 256, 0, stream>>>(qkv, invn, qkt);
    // k6: pack v -> vb bf16 [d][m]
    pack_v<<<(BATCH * 512 * NTOK / 8) / 256, 256, 0, stream>>>(qkv, vb);
    // k7: split-m MFMA flash attention
    attn_mfma<<<dim3(NTOK / 64, BATCH * NH, 2), 256, 0, stream>>>(
        qkt, vb, Opart, statsM, statsS);
    // k8: combine halves -> aoT bf16 [b][n][c]
    attn_combine<<<dim3(NTOK / 64, BATCH * NH), 256, 0, stream>>>(
        Opart, statsM, statsS, aoT);
    // k9: pack w_proj -> bf16 (over dead qkt)
    pack_bf16<<<CIN * HID / 8 / 256, 256, 0, stream>>>(w_proj, wpb, CIN * HID);
    // k10: y = w_proj @ attn_out + bias (MFMA)
    gemm_bf16<HID><<<dim3(NTOK / 128, CIN / 64, BATCH), 256, 0, stream>>>(
        wpb, aoT, b_proj, y, CIN);
}